// Round 4
// baseline (377.774 us; speedup 1.0000x reference)
//
#include <hip/hip_runtime.h>
#include <hip/hip_bf16.h>

typedef __hip_bfloat16 bf16;
typedef short bf16x8 __attribute__((ext_vector_type(8)));
typedef float f32x4 __attribute__((ext_vector_type(4)));

#define NGRAPH 16

// ---------------- K1: prep — casts, weight transposes, graph offsets ----------------
__global__ __launch_bounds__(256) void k_prep(const float* __restrict__ x,
                                              const float* __restrict__ Wqkv,
                                              const float* __restrict__ Wout,
                                              const int* __restrict__ batch,
                                              bf16* __restrict__ xb,
                                              bf16* __restrict__ Wqkv_t,
                                              bf16* __restrict__ Wout_t,
                                              int* __restrict__ offs, int N) {
  int tid = blockIdx.x * 256 + threadIdx.x;
  int T = gridDim.x * 256;
  for (int i = tid; i < N * 256; i += T) xb[i] = __float2bfloat16(x[i]);
  // Wqkv_t[n][k] = Wqkv[k][n]  (768x256 <- 256x768)
  for (int i = tid; i < 768 * 256; i += T) {
    int n = i >> 8, k = i & 255;
    Wqkv_t[i] = __float2bfloat16(Wqkv[k * 768 + n]);
  }
  // Wout_t[n][k] = Wout[k][n]  (256x256)
  for (int i = tid; i < 256 * 256; i += T) {
    int n = i >> 8, k = i & 255;
    Wout_t[i] = __float2bfloat16(Wout[k * 256 + n]);
  }
  for (int i = tid; i < N; i += T) {
    if (i == 0) { offs[0] = 0; offs[NGRAPH] = N; }
    else if (batch[i] != batch[i - 1]) offs[batch[i]] = i;
  }
}

// ---------------- K2: generic MFMA GEMM  C[M,ldc] = A[M,256] @ Bt[ldc,256]^T ----------------
// 64x64 tile per block (4 waves, each wave = 16 rows x 64 cols as 4 mfma tiles).
__global__ __launch_bounds__(256) void k_gemm(const bf16* __restrict__ A,
                                              const bf16* __restrict__ Bt,
                                              float* __restrict__ C, int M, int ldc) {
  __shared__ __align__(16) bf16 As[64][264];   // +8 pad: keeps 16B align, breaks bank stride
  __shared__ __align__(16) bf16 Bs[64][264];
  int t = threadIdx.x;
  int m0 = blockIdx.x * 64, n0 = blockIdx.y * 64;
  {
    int r = t >> 2, c4 = (t & 3) * 64;
    int gm = m0 + r;
    float4* dst = (float4*)&As[r][c4];
    if (gm < M) {
      const float4* src = (const float4*)(A + (size_t)gm * 256 + c4);
      #pragma unroll
      for (int i = 0; i < 8; ++i) dst[i] = src[i];
    } else {
      float4 z = {0.f, 0.f, 0.f, 0.f};
      #pragma unroll
      for (int i = 0; i < 8; ++i) dst[i] = z;
    }
    const float4* srcb = (const float4*)(Bt + (size_t)(n0 + r) * 256 + c4);
    float4* dstb = (float4*)&Bs[r][c4];
    #pragma unroll
    for (int i = 0; i < 8; ++i) dstb[i] = srcb[i];
  }
  __syncthreads();
  int w = t >> 6, l = t & 63;
  int fr = l & 15, fq = l >> 4;
  f32x4 acc[4];
  #pragma unroll
  for (int nt = 0; nt < 4; ++nt) acc[nt] = (f32x4){0.f, 0.f, 0.f, 0.f};
  #pragma unroll
  for (int kt = 0; kt < 8; ++kt) {
    int k0 = kt * 32 + fq * 8;
    bf16x8 a = *(const bf16x8*)&As[w * 16 + fr][k0];
    #pragma unroll
    for (int nt = 0; nt < 4; ++nt) {
      bf16x8 b = *(const bf16x8*)&Bs[nt * 16 + fr][k0];
      acc[nt] = __builtin_amdgcn_mfma_f32_16x16x32_bf16(a, b, acc[nt], 0, 0, 0);
    }
  }
  #pragma unroll
  for (int nt = 0; nt < 4; ++nt) {
    #pragma unroll
    for (int rr = 0; rr < 4; ++rr) {
      int row = m0 + w * 16 + fq * 4 + rr;
      if (row < M) C[(size_t)row * ldc + n0 + nt * 16 + fr] = acc[nt][rr];
    }
  }
}

// ---------------- K3: ragged flash attention w/ RoPE distance bias ----------------
// block = (qtile of 8, graph, head-half of 4 heads); 256 threads; j-tile 64.
__global__ __launch_bounds__(256) void k_attn(const float* __restrict__ pos,
                                              const float* __restrict__ freqs,
                                              const float* __restrict__ Wrope,
                                              const float* __restrict__ QKV,
                                              const int* __restrict__ offs,
                                              bf16* __restrict__ Ob) {
  __shared__ float Qt[8][128];     // [q][h4*32+d], pre-scaled
  __shared__ float S[4][8][65];    // [h4][q][jj]
  __shared__ float wf[16];
  __shared__ float Wr[16][4];
  __shared__ float albuf[4][8];
  int b = blockIdx.y;
  int hbase = blockIdx.z * 4;
  int off = offs[b], n = offs[b + 1] - off;
  int q0 = blockIdx.x * 8;
  if (q0 >= n) return;
  int t = threadIdx.x;
  const float scale = 0.17677669529663687f;  // 32^-0.5

  {
    int idx = t;
    #pragma unroll
    for (int i = 0; i < 4; ++i, idx += 256) {
      int q = idx >> 7, c = idx & 127;
      int qrow = q0 + q;
      Qt[q][c] = (qrow < n) ? QKV[(size_t)(off + qrow) * 768 + hbase * 32 + c] * scale : 0.f;
    }
  }
  if (t < 16) wf[t] = fabsf(freqs[t]);
  if (t < 64) Wr[t >> 2][t & 3] = Wrope[(t >> 2) * 8 + hbase + (t & 3)];

  // phase-role ids
  int q1 = t >> 5, j1 = t & 31;                      // P1: (q, jj-base)
  int h2 = t >> 6, j2 = t & 63;                      // P2: (h, jj)  h == wave id
  int q3 = (t >> 3) & 7, c3 = t & 7;                 // P3: (h, q, chunk)
  int jh = (t >> 5) & 1, dm = t & 31;                // P4: (h, j-half, d)

  float px = 0.f, py = 0.f, pz = 0.f;
  bool vq = (q0 + q1) < n;
  if (vq) { int in_ = (off + q0 + q1) * 3; px = pos[in_]; py = pos[in_ + 1]; pz = pos[in_ + 2]; }

  float o[8];
  #pragma unroll
  for (int q = 0; q < 8; ++q) o[q] = 0.f;
  float mreg = -1e30f, lreg = 0.f;  // softmax state owned by c3==0 lanes
  __syncthreads();

  for (int j0 = 0; j0 < n; j0 += 64) {
    // ---- P1: distance-RoPE bias (cos shared across this block's 4 heads) ----
    #pragma unroll
    for (int half = 0; half < 2; ++half) {
      int jg = j0 + j1 + half * 32;
      bool vj = jg < n;
      float bv[4] = {0.f, 0.f, 0.f, 0.f};
      if (vj && vq) {
        int jn = (off + jg) * 3;
        float dx = px - pos[jn], dy = py - pos[jn + 1], dz = pz - pos[jn + 2];
        float dist = sqrtf(dx * dx + dy * dy + dz * dz);
        #pragma unroll
        for (int r2 = 0; r2 < 16; ++r2) {
          float cv = __cosf(dist * wf[r2]);
          #pragma unroll
          for (int h = 0; h < 4; ++h) bv[h] += cv * Wr[r2][h];
        }
      }
      #pragma unroll
      for (int h = 0; h < 4; ++h) S[h][q1][j1 + half * 32] = vj ? bv[h] : -1e30f;
    }
    __syncthreads();
    // ---- P2: S += Q.K^T (wave = head, lane = j; K segment register-cached over 8 q) ----
    {
      int jg = j0 + j2;
      if (jg < n) {
        float kreg[32];
        const float4* kp = (const float4*)(QKV + (size_t)(off + jg) * 768 + 256 + (hbase + h2) * 32);
        #pragma unroll
        for (int i = 0; i < 8; ++i) {
          float4 kk = kp[i];
          kreg[i * 4] = kk.x; kreg[i * 4 + 1] = kk.y; kreg[i * 4 + 2] = kk.z; kreg[i * 4 + 3] = kk.w;
        }
        #pragma unroll
        for (int q = 0; q < 8; ++q) {
          float dot = 0.f;
          #pragma unroll
          for (int d4 = 0; d4 < 8; ++d4) {
            float4 qv = *(const float4*)&Qt[q][h2 * 32 + d4 * 4];
            dot += qv.x * kreg[d4 * 4] + qv.y * kreg[d4 * 4 + 1]
                 + qv.z * kreg[d4 * 4 + 2] + qv.w * kreg[d4 * 4 + 3];
          }
          S[h2][q][j2] += dot;
        }
      }
    }
    __syncthreads();
    // ---- P3: online softmax, 8 lanes per (h,q), shfl-combined ----
    {
      float sv[8];
      float mrow = -1e30f;
      #pragma unroll
      for (int i = 0; i < 8; ++i) { sv[i] = S[h2][q3][c3 * 8 + i]; mrow = fmaxf(mrow, sv[i]); }
      #pragma unroll
      for (int m2 = 1; m2 <= 4; m2 <<= 1) mrow = fmaxf(mrow, __shfl_xor(mrow, m2));
      float mold = __shfl(mreg, (t & 63) & ~7);
      float mnew = fmaxf(mold, mrow);
      float s = 0.f;
      #pragma unroll
      for (int i = 0; i < 8; ++i) {
        float p = __expf(sv[i] - mnew);
        S[h2][q3][c3 * 8 + i] = p;
        s += p;
      }
      #pragma unroll
      for (int m2 = 1; m2 <= 4; m2 <<= 1) s += __shfl_xor(s, m2);
      if (c3 == 0) {
        float a = __expf(mreg - mnew);
        lreg = lreg * a + s;
        mreg = mnew;
        albuf[h2][q3] = a;
      }
    }
    __syncthreads();
    // ---- P4: O accumulate (each lane owns (h,dm), j-halves split across lane pairs) ----
    {
      #pragma unroll
      for (int q = 0; q < 8; ++q) o[q] *= albuf[h2][q];
      int jmax = n - j0; if (jmax > 64) jmax = 64;
      int jlo = jh * 32, jhi = jmax < jlo + 32 ? jmax : jlo + 32;
      for (int jj = jlo; jj < jhi; ++jj) {
        float v = QKV[(size_t)(off + j0 + jj) * 768 + 512 + (hbase + h2) * 32 + dm];
        #pragma unroll
        for (int q = 0; q < 8; ++q) o[q] += S[h2][q][jj] * v;
      }
    }
    __syncthreads();
  }

  if (c3 == 0) albuf[h2][q3] = lreg;  // final l
  __syncthreads();
  #pragma unroll
  for (int q = 0; q < 8; ++q) {
    float oq = o[q] + __shfl_xor(o[q], 32);
    if (jh == 0 && (q0 + q) < n) {
      Ob[(size_t)(off + q0 + q) * 256 + (hbase + h2) * 32 + dm] =
          __float2bfloat16(oq / albuf[h2][q]);
    }
  }
}

// ---------------- K4: residual + LayerNorm (GEMM done by k_gemm) ----------------
__global__ __launch_bounds__(256) void k_ln(const float* __restrict__ x,
                                            const float* __restrict__ Y,
                                            const float* __restrict__ gamma,
                                            const float* __restrict__ beta,
                                            float* __restrict__ out, int N) {
  int t = threadIdx.x;
  int w = t >> 6, lane = t & 63;
  int row = blockIdx.x * 4 + w;
  if (row >= N) return;
  float v[4];
  float s = 0.f, ss = 0.f;
  #pragma unroll
  for (int i = 0; i < 4; ++i) {
    int c = lane + 64 * i;
    v[i] = x[(size_t)row * 256 + c] + Y[(size_t)row * 256 + c];
    s += v[i]; ss += v[i] * v[i];
  }
  #pragma unroll
  for (int m = 32; m >= 1; m >>= 1) { s += __shfl_xor(s, m); ss += __shfl_xor(ss, m); }
  float mean = s * (1.f / 256.f);
  float var = ss * (1.f / 256.f) - mean * mean;
  float rstd = rsqrtf(var + 1e-5f);
  #pragma unroll
  for (int i = 0; i < 4; ++i) {
    int c = lane + 64 * i;
    out[(size_t)row * 256 + c] = gamma[c] * (v[i] - mean) * rstd + beta[c];
  }
}

extern "C" void kernel_launch(void* const* d_in, const int* in_sizes, int n_in,
                              void* d_out, int out_size, void* d_ws, size_t ws_size,
                              hipStream_t stream) {
  (void)n_in; (void)out_size; (void)ws_size;
  const float* x     = (const float*)d_in[0];
  const float* pos   = (const float*)d_in[1];
  const int*   batch = (const int*)d_in[2];
  const float* Wqkv  = (const float*)d_in[3];
  const float* Wout  = (const float*)d_in[4];
  const float* freqs = (const float*)d_in[5];
  const float* Wrope = (const float*)d_in[6];
  const float* gamma = (const float*)d_in[7];
  const float* beta  = (const float*)d_in[8];
  float* out = (float*)d_out;

  int N = in_sizes[0] / 256;  // 6137

  // ws layout (16B aligned); Ob aliases xb (xb dead after gemm1), Y aliases QKV (dead after attn)
  char* base = (char*)d_ws;
  int*   offs    = (int*)base;                               // 68 B
  float* QKV     = (float*)(base + 1024);                    // N*768*4
  size_t o_xb    = 1024 + (size_t)N * 3072;
  bf16*  xb      = (bf16*)(base + o_xb);                     // N*256*2
  size_t o_wq    = o_xb + (size_t)N * 512;
  bf16*  Wqkv_t  = (bf16*)(base + o_wq);                     // 768*256*2
  size_t o_wo    = o_wq + 768 * 256 * 2;
  bf16*  Wout_t  = (bf16*)(base + o_wo);                     // 256*256*2
  bf16*  Ob      = xb;                                       // alias
  float* Y       = QKV;                                      // alias

  k_prep<<<1536, 256, 0, stream>>>(x, Wqkv, Wout, batch, xb, Wqkv_t, Wout_t, offs, N);
  k_gemm<<<dim3((N + 63) / 64, 12), 256, 0, stream>>>(xb, Wqkv_t, QKV, N, 768);
  k_attn<<<dim3(64, NGRAPH, 2), 256, 0, stream>>>(pos, freqs, Wrope, QKV, offs, Ob);
  k_gemm<<<dim3((N + 63) / 64, 4), 256, 0, stream>>>(Ob, Wout_t, Y, N, 256);
  k_ln<<<(N + 3) / 4, 256, 0, stream>>>(x, Y, gamma, beta, out, N);
}

// Round 5
// 190.447 us; speedup vs baseline: 1.9836x; 1.9836x over previous
//
#include <hip/hip_runtime.h>
#include <hip/hip_bf16.h>

typedef __hip_bfloat16 bf16;
typedef short bf16x8 __attribute__((ext_vector_type(8)));
typedef float f32x4 __attribute__((ext_vector_type(4)));

#define NGRAPH 16
#define QSCALE 0.17677669529663687f
#define VT_LD 8192  // V^T leading dim: 16 graphs x 512 slots (per-graph 16B-aligned)

// ---------------- K1: prep — x cast, weight transposes, graph offsets ----------------
__global__ __launch_bounds__(256) void k_prep(const float* __restrict__ x,
                                              const float* __restrict__ Wqkv,
                                              const float* __restrict__ Wout,
                                              const int* __restrict__ batch,
                                              bf16* __restrict__ xb,
                                              bf16* __restrict__ Wqkv_t,
                                              bf16* __restrict__ Wout_t,
                                              int* __restrict__ offs, int N) {
  int tid = blockIdx.x * 256 + threadIdx.x;
  int T = gridDim.x * 256;
  for (int i = tid; i < N * 256; i += T) xb[i] = __float2bfloat16(x[i]);
  for (int i = tid; i < 768 * 256; i += T) {
    int n = i >> 8, k = i & 255;
    Wqkv_t[i] = __float2bfloat16(Wqkv[k * 768 + n]);
  }
  for (int i = tid; i < 256 * 256; i += T) {
    int n = i >> 8, k = i & 255;
    Wout_t[i] = __float2bfloat16(Wout[k * 256 + n]);
  }
  for (int i = tid; i < N; i += T) {
    if (i == 0) { offs[0] = 0; offs[NGRAPH] = N; }
    else if (batch[i] != batch[i - 1]) offs[batch[i]] = i;
  }
}

// ---------------- K2: QKV GEMM, LDS-free MFMA. C bf16 (Q scaled) + V^T side output ----
// block = 64m x 64n, 4 waves, wave = 16 rows. All frags = direct 16B global loads.
__global__ __launch_bounds__(256) void k_gemm_qkv(const bf16* __restrict__ A,
                                                  const bf16* __restrict__ Bt,
                                                  const int* __restrict__ batch,
                                                  const int* __restrict__ offs,
                                                  bf16* __restrict__ C,
                                                  bf16* __restrict__ VT, int M) {
  __shared__ float tr[64][65];
  __shared__ int rowcol[64];
  int t = threadIdx.x, w = t >> 6, l = t & 63, fr = l & 15, fq = l >> 4;
  int m0 = blockIdx.x * 64, n0 = blockIdx.y * 64;
  bool isV = (n0 >= 512);
  if (isV && t < 64) {
    int m = m0 + t; if (m > M - 1) m = M - 1;
    int b = batch[m];
    rowcol[t] = b * 512 + (m - offs[b]);
  }
  int arow = m0 + w * 16 + fr; if (arow > M - 1) arow = M - 1;
  bf16x8 af[8];
  #pragma unroll
  for (int kt = 0; kt < 8; ++kt)
    af[kt] = *(const bf16x8*)(A + (size_t)arow * 256 + kt * 32 + fq * 8);
  f32x4 acc[4];
  #pragma unroll
  for (int nt = 0; nt < 4; ++nt) acc[nt] = (f32x4){0.f, 0.f, 0.f, 0.f};
  #pragma unroll
  for (int nt = 0; nt < 4; ++nt) {
    int brow = n0 + nt * 16 + fr;
    #pragma unroll
    for (int kt = 0; kt < 8; ++kt) {
      bf16x8 bf_ = *(const bf16x8*)(Bt + (size_t)brow * 256 + kt * 32 + fq * 8);
      acc[nt] = __builtin_amdgcn_mfma_f32_16x16x32_bf16(af[kt], bf_, acc[nt], 0, 0, 0);
    }
  }
  #pragma unroll
  for (int nt = 0; nt < 4; ++nt) {
    int col = n0 + nt * 16 + fr;
    float sc = (col < 256) ? QSCALE : 1.f;
    #pragma unroll
    for (int rr = 0; rr < 4; ++rr) {
      int m = m0 + w * 16 + fq * 4 + rr;
      if (m < M) C[(size_t)m * 768 + col] = __float2bfloat16(acc[nt][rr] * sc);
    }
  }
  if (isV) {
    #pragma unroll
    for (int nt = 0; nt < 4; ++nt)
      #pragma unroll
      for (int rr = 0; rr < 4; ++rr)
        tr[nt * 16 + fr][w * 16 + fq * 4 + rr] = acc[nt][rr];
    __syncthreads();
    int c = t >> 2, r0 = (t & 3) * 16;
    int dg = (n0 - 512) + c;  // head*32 + d
    #pragma unroll
    for (int i = 0; i < 16; ++i) {
      int r = r0 + i;
      VT[(size_t)dg * VT_LD + rowcol[r]] = __float2bfloat16(tr[c][r]);
    }
  }
}

// ---------------- K3: MFMA flash attention w/ RoPE distance bias ----------------
// block = (q-tile 16, graph, head-half of 4). 4 waves, wave = one head.
// One mfma = full 16q x 16j S-tile (hd = 32 = K). 1 barrier per 32-j tile.
__global__ __launch_bounds__(256) void k_attn(const float* __restrict__ pos,
                                              const float* __restrict__ freqs,
                                              const float* __restrict__ Wrope,
                                              const bf16* __restrict__ QKVb,
                                              const bf16* __restrict__ VT,
                                              const int* __restrict__ offs,
                                              bf16* __restrict__ Ob) {
  __shared__ float Sb[2][4][16][34];            // double-buffered bias tiles
  __shared__ __align__(16) bf16 Pt[4][16][40];  // per-wave P (C->A transform)
  __shared__ float wf[16];
  __shared__ float Wr[16][4];
  int b = blockIdx.y, hbase = blockIdx.z * 4;
  int off = offs[b], n = offs[b + 1] - off;
  int q0 = blockIdx.x * 16;
  if (q0 >= n) return;
  int t = threadIdx.x, w = t >> 6, l = t & 63, fr = l & 15, fq = l >> 4;
  int h = hbase + w;
  if (t < 16) wf[t] = fabsf(freqs[t]);
  if (t < 64) Wr[t >> 2][t & 3] = Wrope[(t >> 2) * 8 + hbase + (t & 3)];
  // Q A-frag: lane holds Q[m = fr][k = fq*8..+8] (pre-scaled bf16)
  int qrow = q0 + fr; bool qv = qrow < n;
  bf16x8 aq = *(const bf16x8*)(QKVb + (size_t)((qv ? off + qrow : off)) * 768 + h * 32 + fq * 8);
  if (!qv) aq = (bf16x8){0, 0, 0, 0, 0, 0, 0, 0};
  // bias-producer role: this thread owns pairs (q = bq, j = bj) and (q = bq+8, j = bj)
  int bq = t >> 5, bj = t & 31;
  float qpx[2], qpy[2], qpz[2]; bool bqv[2];
  #pragma unroll
  for (int e = 0; e < 2; ++e) {
    int qq = q0 + bq + 8 * e; bqv[e] = qq < n;
    int a = (bqv[e] ? off + qq : off) * 3;
    qpx[e] = pos[a]; qpy[e] = pos[a + 1]; qpz[e] = pos[a + 2];
  }
  float m_st[4], l_st[4]; f32x4 Oa[2];
  #pragma unroll
  for (int rr = 0; rr < 4; ++rr) { m_st[rr] = -1e30f; l_st[rr] = 0.f; }
  Oa[0] = (f32x4){0.f, 0.f, 0.f, 0.f}; Oa[1] = (f32x4){0.f, 0.f, 0.f, 0.f};
  __syncthreads();

  int par = 0;
  for (int j0 = 0; j0 < n; j0 += 32, par ^= 1) {
    // ---- bias tile [4h][16q][32j]: cos computed once per pair, shared by 4 heads ----
    {
      int jg = j0 + bj; bool vj = jg < n;
      int a = (vj ? off + jg : off) * 3;
      float jx = pos[a], jy = pos[a + 1], jz = pos[a + 2];
      #pragma unroll
      for (int e = 0; e < 2; ++e) {
        float bv0 = 0.f, bv1 = 0.f, bv2 = 0.f, bv3 = 0.f;
        if (vj && bqv[e]) {
          float dx = qpx[e] - jx, dy = qpy[e] - jy, dz = qpz[e] - jz;
          float dist = sqrtf(dx * dx + dy * dy + dz * dz);
          #pragma unroll
          for (int r = 0; r < 16; ++r) {
            float cv = __cosf(dist * wf[r]);
            bv0 += cv * Wr[r][0]; bv1 += cv * Wr[r][1];
            bv2 += cv * Wr[r][2]; bv3 += cv * Wr[r][3];
          }
        }
        int qi = bq + 8 * e;
        Sb[par][0][qi][bj] = vj ? bv0 : -1e30f;
        Sb[par][1][qi][bj] = vj ? bv1 : -1e30f;
        Sb[par][2][qi][bj] = vj ? bv2 : -1e30f;
        Sb[par][3][qi][bj] = vj ? bv3 : -1e30f;
      }
    }
    __syncthreads();  // bias[par] ready; prev-iter Sb[par] reads all complete (2 bars back)
    // ---- QK^T: 2 mfmas (16j each), K B-frag = direct 16B global load ----
    f32x4 Sv[2];
    #pragma unroll
    for (int jt = 0; jt < 2; ++jt) {
      int krow = j0 + jt * 16 + fr;
      bf16x8 bk = *(const bf16x8*)(QKVb + (size_t)((krow < n) ? off + krow : off) * 768 + 256 + h * 32 + fq * 8);
      f32x4 z = {0.f, 0.f, 0.f, 0.f};
      Sv[jt] = __builtin_amdgcn_mfma_f32_16x16x32_bf16(aq, bk, z, 0, 0, 0);
      #pragma unroll
      for (int rr = 0; rr < 4; ++rr) Sv[jt][rr] += Sb[par][w][fq * 4 + rr][jt * 16 + fr];
    }
    // ---- online softmax in C-layout regs (row = fq*4+rr lives in 16-lane group) ----
    #pragma unroll
    for (int rr = 0; rr < 4; ++rr) {
      float mrow = fmaxf(Sv[0][rr], Sv[1][rr]);
      #pragma unroll
      for (int m2 = 1; m2 <= 8; m2 <<= 1) mrow = fmaxf(mrow, __shfl_xor(mrow, m2));
      float mnew = fmaxf(m_st[rr], mrow);
      float al = __expf(m_st[rr] - mnew);
      m_st[rr] = mnew;
      float p0 = __expf(Sv[0][rr] - mnew), p1 = __expf(Sv[1][rr] - mnew);
      Sv[0][rr] = p0; Sv[1][rr] = p1;
      float rs = p0 + p1;
      #pragma unroll
      for (int m2 = 1; m2 <= 8; m2 <<= 1) rs += __shfl_xor(rs, m2);
      l_st[rr] = l_st[rr] * al + rs;
      Oa[0][rr] *= al; Oa[1][rr] *= al;
    }
    // ---- P: C-layout -> A-layout via per-wave LDS tile (no barrier needed) ----
    #pragma unroll
    for (int jt = 0; jt < 2; ++jt)
      #pragma unroll
      for (int rr = 0; rr < 4; ++rr)
        Pt[w][fq * 4 + rr][jt * 16 + fr] = __float2bfloat16(Sv[jt][rr]);
    bf16x8 ap = *(const bf16x8*)&Pt[w][fr][fq * 8];
    // ---- PV: 2 mfmas (16d each), V B-frag = direct 16B load from V^T ----
    #pragma unroll
    for (int dh = 0; dh < 2; ++dh) {
      bf16x8 bv = *(const bf16x8*)(VT + (size_t)(h * 32 + dh * 16 + fr) * VT_LD + b * 512 + j0 + fq * 8);
      Oa[dh] = __builtin_amdgcn_mfma_f32_16x16x32_bf16(ap, bv, Oa[dh], 0, 0, 0);
    }
  }
  #pragma unroll
  for (int dh = 0; dh < 2; ++dh)
    #pragma unroll
    for (int rr = 0; rr < 4; ++rr) {
      int row = q0 + fq * 4 + rr;
      if (row < n)
        Ob[(size_t)(off + row) * 256 + h * 32 + dh * 16 + fr] =
            __float2bfloat16(Oa[dh][rr] / l_st[rr]);
    }
}

// ---------------- K4: out-proj GEMM, LDS-free MFMA, f32 out ----------------
__global__ __launch_bounds__(256) void k_gemm_out(const bf16* __restrict__ A,
                                                  const bf16* __restrict__ Bt,
                                                  float* __restrict__ C, int M) {
  int t = threadIdx.x, w = t >> 6, l = t & 63, fr = l & 15, fq = l >> 4;
  int m0 = blockIdx.x * 64, n0 = blockIdx.y * 64;
  int arow = m0 + w * 16 + fr; if (arow > M - 1) arow = M - 1;
  bf16x8 af[8];
  #pragma unroll
  for (int kt = 0; kt < 8; ++kt)
    af[kt] = *(const bf16x8*)(A + (size_t)arow * 256 + kt * 32 + fq * 8);
  f32x4 acc[4];
  #pragma unroll
  for (int nt = 0; nt < 4; ++nt) acc[nt] = (f32x4){0.f, 0.f, 0.f, 0.f};
  #pragma unroll
  for (int nt = 0; nt < 4; ++nt) {
    int brow = n0 + nt * 16 + fr;
    #pragma unroll
    for (int kt = 0; kt < 8; ++kt) {
      bf16x8 bf_ = *(const bf16x8*)(Bt + (size_t)brow * 256 + kt * 32 + fq * 8);
      acc[nt] = __builtin_amdgcn_mfma_f32_16x16x32_bf16(af[kt], bf_, acc[nt], 0, 0, 0);
    }
  }
  #pragma unroll
  for (int nt = 0; nt < 4; ++nt) {
    int col = n0 + nt * 16 + fr;
    #pragma unroll
    for (int rr = 0; rr < 4; ++rr) {
      int m = m0 + w * 16 + fq * 4 + rr;
      if (m < M) C[(size_t)m * 256 + col] = acc[nt][rr];
    }
  }
}

// ---------------- K5: residual + LayerNorm ----------------
__global__ __launch_bounds__(256) void k_ln(const float* __restrict__ x,
                                            const float* __restrict__ Y,
                                            const float* __restrict__ gamma,
                                            const float* __restrict__ beta,
                                            float* __restrict__ out, int N) {
  int t = threadIdx.x;
  int w = t >> 6, lane = t & 63;
  int row = blockIdx.x * 4 + w;
  if (row >= N) return;
  float v[4];
  float s = 0.f, ss = 0.f;
  #pragma unroll
  for (int i = 0; i < 4; ++i) {
    int c = lane + 64 * i;
    v[i] = x[(size_t)row * 256 + c] + Y[(size_t)row * 256 + c];
    s += v[i]; ss += v[i] * v[i];
  }
  #pragma unroll
  for (int m = 32; m >= 1; m >>= 1) { s += __shfl_xor(s, m); ss += __shfl_xor(ss, m); }
  float mean = s * (1.f / 256.f);
  float var = ss * (1.f / 256.f) - mean * mean;
  float rstd = rsqrtf(var + 1e-5f);
  #pragma unroll
  for (int i = 0; i < 4; ++i) {
    int c = lane + 64 * i;
    out[(size_t)row * 256 + c] = gamma[c] * (v[i] - mean) * rstd + beta[c];
  }
}

extern "C" void kernel_launch(void* const* d_in, const int* in_sizes, int n_in,
                              void* d_out, int out_size, void* d_ws, size_t ws_size,
                              hipStream_t stream) {
  (void)n_in; (void)out_size; (void)ws_size;
  const float* x     = (const float*)d_in[0];
  const float* pos   = (const float*)d_in[1];
  const int*   batch = (const int*)d_in[2];
  const float* Wqkv  = (const float*)d_in[3];
  const float* Wout  = (const float*)d_in[4];
  const float* freqs = (const float*)d_in[5];
  const float* Wrope = (const float*)d_in[6];
  const float* gamma = (const float*)d_in[7];
  const float* beta  = (const float*)d_in[8];
  float* out = (float*)d_out;

  int N = in_sizes[0] / 256;  // 6137

  char* base = (char*)d_ws;
  int*   offs   = (int*)base;                                   // @0
  bf16*  QKVb   = (bf16*)(base + 1024);                         // N*768*2  = 9,426,432
  bf16*  VT     = (bf16*)(base + 9427456);                      // 256*8192*2 = 4,194,304
  bf16*  xb     = (bf16*)(base + 13621760);                     // N*256*2  = 3,142,144
  bf16*  Wqkv_t = (bf16*)(base + 16763904);                     // 393,216
  bf16*  Wout_t = (bf16*)(base + 17157120);                     // 131,072
  float* Y      = (float*)(base + 17288192);                    // N*256*4
  bf16*  Ob     = xb;  // xb dead after gemm1

  int MB = (N + 63) / 64;  // 96
  k_prep<<<1024, 256, 0, stream>>>(x, Wqkv, Wout, batch, xb, Wqkv_t, Wout_t, offs, N);
  k_gemm_qkv<<<dim3(MB, 12), 256, 0, stream>>>(xb, Wqkv_t, batch, offs, QKVb, VT, N);
  k_attn<<<dim3(32, NGRAPH, 2), 256, 0, stream>>>(pos, freqs, Wrope, QKVb, VT, offs, Ob);
  k_gemm_out<<<dim3(MB, 4), 256, 0, stream>>>(Ob, Wout_t, Y, N);
  k_ln<<<(N + 3) / 4, 256, 0, stream>>>(x, Y, gamma, beta, out, N);
}